// Round 13
// baseline (27.377 us; speedup 1.0000x reference)
//
#include <hip/hip_runtime.h>
#include <cfloat>

// Problem constants: B=32, C=256, L=512, N=1024, S=8
constexpr int Bc = 32;
constexpr int Cc = 256;
constexpr int Lc = 512;
constexpr int Nc = 1024;
constexpr int Sc = 8;

constexpr int CT = 8;         // channels per block

typedef float f4 __attribute__((ext_vector_type(4)));

// masked max over chunk elements [lo, hi) (cndmask, no branch); full chunks
// (lo<=0, hi>=4) reduce to plain 4-max.
__device__ __forceinline__ float chunkmax(f4 v, int lo, int hi, float m) {
    float a0 = (lo <= 0 && 0 < hi) ? v.x : -FLT_MAX;
    float a1 = (lo <= 1 && 1 < hi) ? v.y : -FLT_MAX;
    float a2 = (lo <= 2 && 2 < hi) ? v.z : -FLT_MAX;
    float a3 = (lo <= 3 && 3 < hi) ? v.w : -FLT_MAX;
    return fmaxf(fmaxf(m, fmaxf(a0, a1)), fmaxf(a2, a3));
}

// rotated chunk slot: row r, f4-chunk q -> float offset in rowbuf.
// Rotation (q + 4r) & 127 puts row r's chunk q at bank-quad (q + 4r) % 32:
// walk lanes (cl fixed-q) land 4 quads apart -> conflict-free; staging writes
// (consecutive q within a row) stay consecutive -> conflict-free.
__device__ __forceinline__ int slot(int r, int q) {
    return r * Lc + 4 * ((q + 4 * r) & 127);
}

// Block = (batch b, 8-channel tile, item-parity half). 2048 blocks,
// 18.1 KB LDS + <=64 VGPR -> 8 blocks/CU = 32 waves/CU (2x all prior rounds).
// Same proven-deterministic skeleton: ballot compaction -> staging in-loop ->
// barrier -> prefix -> list -> barrier -> walk.
__global__ __launch_bounds__(256, 8) void roi_pool_hiocc(
    const float* __restrict__ sentences,   // (B, C, L)
    const int*   __restrict__ rois,        // (N, 2)
    const int*   __restrict__ roi_idx,     // (N,)
    float*       __restrict__ out)         // (N, C, S)
{
    __shared__ float          rowbuf[CT * Lc];  // 16,384 B (rotated, no pad)
    __shared__ unsigned short list[Nc];         //  2,048 B (worst-case safe)
    __shared__ int            wcnt[16];

    const int bid  = blockIdx.x;           // 0..2047
    const int b    = bid >> 6;             // batch
    const int ct   = (bid >> 1) & 31;      // channel tile
    const int half = bid & 1;              // item parity
    const int c0   = ct * CT;

    const int tid  = threadIdx.x;
    const int lane = tid & 63;
    const int w    = tid >> 6;             // wave 0..3

    // ---- ballot compaction scan (proven R8/R11/R12) ----
    int myn[4], mypos[4];
    #pragma unroll
    for (int q = 0; q < 4; ++q) {
        const int i = q * 256 + tid;
        const int v = roi_idx[i];
        const unsigned long long mask = __ballot(v == b);
        mypos[q] = __popcll(mask & ((1ull << lane) - 1ull));
        myn[q]   = (v == b) ? i : -1;
        if (lane == 0) wcnt[q * 4 + w] = __popcll(mask);
    }

    // ---- staging: load -> rotated ds_write in-loop ----
    {
        const f4* src = (const f4*)(sentences + ((size_t)b * Cc + c0) * Lc);
        #pragma unroll
        for (int i = 0; i < 4; ++i) {
            const int idx = tid + i * 256;            // 0..1023
            const int r   = idx >> 7;                 // row 0..7
            const int q   = idx & 127;                // f4 chunk
            f4 v = src[r * 128 + q];                  // coalesced 1KB/wave
            *(f4*)(rowbuf + slot(r, q)) = v;          // aligned b128, conflict-free
        }
    }
    __syncthreads();   // wcnt + rowbuf visible

    // ---- deterministic prefix over wcnt (verbatim) ----
    int wb0 = 0, wb1 = 0, wb2 = 0, wb3 = 0, run = 0;
    #pragma unroll
    for (int t = 0; t < 16; ++t) {
        if (t == w)      wb0 = run;
        if (t == 4 + w)  wb1 = run;
        if (t == 8 + w)  wb2 = run;
        if (t == 12 + w) wb3 = run;
        run += wcnt[t];
    }
    const int m = run;                     // bucket size for batch b

    if (myn[0] >= 0) list[wb0 + mypos[0]] = (unsigned short)myn[0];
    if (myn[1] >= 0) list[wb1 + mypos[1]] = (unsigned short)myn[1];
    if (myn[2] >= 0) list[wb2 + mypos[2]] = (unsigned short)myn[2];
    if (myn[3] >= 0) list[wb3 + mypos[3]] = (unsigned short)myn[3];
    __syncthreads();   // list visible

    // ---- bin maxes: items of parity `half`; wave w takes every 4th ----
    const int cl = lane >> 3;              // channel within tile 0..7
    const int j  = lane & 7;               // bin

    for (int i = half + 2 * w; i < m; i += 8) {
        const int n  = list[i];            // wave-uniform LDS broadcast
        const int x1 = rois[2 * n];        // L2-hot (16 KB table)
        const int x2 = rois[2 * n + 1];
        const int lr = x2 - x1;            // 1..512
        const int s  = x1 + ((j * lr) >> 3);
        const int e  = x1 + (((j + 1) * lr + Sc - 1) >> 3);   // > s always

        const int qs = s >> 2;
        const int qe = (e - 1) >> 2;       // inclusive last chunk, <=127

        float mm = -FLT_MAX;
        for (int q = qs; q <= qe; ++q) {
            f4 v = *(const f4*)(rowbuf + slot(cl, q));
            mm = chunkmax(v, s - 4 * q, e - 4 * q, mm);   // interior -> full 4-max
        }

        // lanes (cl,j) -> 64 consecutive floats: coalesced 256B store
        out[(size_t)n * (Cc * Sc) + (c0 + cl) * Sc + j] = mm;
    }
}

extern "C" void kernel_launch(void* const* d_in, const int* in_sizes, int n_in,
                              void* d_out, int out_size, void* d_ws, size_t ws_size,
                              hipStream_t stream) {
    const float* sentences = (const float*)d_in[0];
    const int*   rois      = (const int*)d_in[1];
    const int*   roi_idx   = (const int*)d_in[2];
    float*       out       = (float*)d_out;

    roi_pool_hiocc<<<Bc * (Cc / CT) * 2, 256, 0, stream>>>(sentences, rois, roi_idx, out);
}

// Round 14
// 20.167 us; speedup vs baseline: 1.3575x; 1.3575x over previous
//
#include <hip/hip_runtime.h>
#include <cfloat>

// Problem constants: B=32, C=256, L=512, N=1024, S=8
constexpr int Bc = 32;
constexpr int Cc = 256;
constexpr int Lc = 512;
constexpr int Nc = 1024;
constexpr int Sc = 8;

constexpr int CT      = 4;    // channels per block
constexpr int STRIDE  = 524;  // rowbuf stride: quad bank = 3*cl + q -> spread
constexpr int LSTRIDE = 133;  // lvl1 stride: bank = 5*cl + q -> spread

typedef float f4 __attribute__((ext_vector_type(4)));

// masked max over chunk elements [lo, hi) (cndmask, no branch)
__device__ __forceinline__ float chunkmax(f4 v, int lo, int hi, float m) {
    float a0 = (lo <= 0 && 0 < hi) ? v.x : -FLT_MAX;
    float a1 = (lo <= 1 && 1 < hi) ? v.y : -FLT_MAX;
    float a2 = (lo <= 2 && 2 < hi) ? v.z : -FLT_MAX;
    float a3 = (lo <= 3 && 3 < hi) ? v.w : -FLT_MAX;
    return fmaxf(fmaxf(m, fmaxf(a0, a1)), fmaxf(a2, a3));
}

// Block = (batch b, 4-channel tile): 2048 blocks, 14.7 KB LDS, <=64 VGPR
// -> 8 resident blocks/CU = 32 waves/CU (2x every prior round).
// Phase skeleton identical to R11/R12 (proven deterministic); walk processes
// 2 items per wave: lane = (ip:1, cl:2, j:3).
__global__ __launch_bounds__(256, 8) void roi_pool_occ8(
    const float* __restrict__ sentences,   // (B, C, L)
    const int*   __restrict__ rois,        // (N, 2)
    const int*   __restrict__ roi_idx,     // (N,)
    float*       __restrict__ out)         // (N, C, S)
{
    __shared__ __align__(16) float rowbuf[CT * STRIDE];   // 8,384 B
    __shared__ float lvl1[CT * LSTRIDE];                  // 2,128 B
    __shared__ int   list[Nc];                            // 4 KB: n | x1<<10 | x2<<20
    __shared__ int   wcnt[16];

    const int bid  = blockIdx.x;           // 0..2047
    const int b    = bid >> 6;             // batch
    const int c0   = (bid & 63) * CT;      // channel tile base
    const int tid  = threadIdx.x;
    const int lane = tid & 63;
    const int w    = tid >> 6;             // wave 0..3

    // ---- ballot compaction scan + rois packing (verbatim R12) ----
    int mypack[4], mypos[4];
    #pragma unroll
    for (int q = 0; q < 4; ++q) {
        const int i = q * 256 + tid;
        const int v = roi_idx[i];
        const unsigned long long mask = __ballot(v == b);
        mypos[q] = __popcll(mask & ((1ull << lane) - 1ull));
        if (v == b) {
            const int xx1 = rois[2 * i];
            const int xx2 = rois[2 * i + 1];
            mypack[q] = i | (xx1 << 10) | (xx2 << 20);   // n:10 | x1:10 | x2:10
        } else {
            mypack[q] = -1;
        }
        if (lane == 0) wcnt[q * 4 + w] = __popcll(mask);
    }

    // ---- staging: load -> ds_write in-loop + level-1 pyramid (verbatim) ----
    {
        const f4* src = (const f4*)(sentences + ((size_t)b * Cc + c0) * Lc);
        #pragma unroll
        for (int i = 0; i < (CT * Lc / 4) / 256; ++i) {   // 2 chunks/thread
            const int idx = tid + i * 256;                // 0..511
            const int r   = idx >> 7;                     // row 0..3
            const int q   = idx & 127;                    // f4 slot
            f4 v = src[r * (Lc / 4) + q];                 // coalesced 1KB/wave
            *(f4*)(rowbuf + r * STRIDE + 4 * q) = v;      // aligned ds_write_b128
            lvl1[r * LSTRIDE + q] = fmaxf(fmaxf(v.x, v.y), fmaxf(v.z, v.w));
        }
    }
    __syncthreads();   // wcnt + rowbuf + lvl1 visible

    // ---- deterministic prefix over wcnt (verbatim) ----
    int wb0 = 0, wb1 = 0, wb2 = 0, wb3 = 0, run = 0;
    #pragma unroll
    for (int t = 0; t < 16; ++t) {
        if (t == w)      wb0 = run;
        if (t == 4 + w)  wb1 = run;
        if (t == 8 + w)  wb2 = run;
        if (t == 12 + w) wb3 = run;
        run += wcnt[t];
    }
    const int m = run;                     // bucket size for batch b

    if (mypack[0] >= 0) list[wb0 + mypos[0]] = mypack[0];
    if (mypack[1] >= 0) list[wb1 + mypos[1]] = mypack[1];
    if (mypack[2] >= 0) list[wb2 + mypos[2]] = mypack[2];
    if (mypack[3] >= 0) list[wb3 + mypos[3]] = mypack[3];
    __syncthreads();   // list visible

    // ---- bin maxes: 2 items per wave; lane = (ip, cl, j) ----
    const int ip = lane >> 5;              // item slot 0/1
    const int cl = (lane >> 3) & 3;        // channel within tile
    const int j  = lane & 7;               // bin
    const float* row = rowbuf + cl * STRIDE;
    const float* lv  = lvl1 + cl * LSTRIDE;

    for (int i2 = 2 * w; i2 < m; i2 += 8) {
        const int item  = i2 + ip;
        const bool valid = item < m;                 // half-wave guard
        const int v  = list[valid ? item : i2];      // i2 < m guaranteed

        const int n  = v & 1023;
        const int x1 = (v >> 10) & 1023;
        const int x2 = v >> 20;
        const int lr = x2 - x1;            // 1..512
        const int s  = x1 + ((j * lr) >> 3);
        const int e  = x1 + (((j + 1) * lr + Sc - 1) >> 3);   // > s always

        const int qs = s >> 2;
        const int qe = e >> 2;

        // head chunk — masked f4
        f4 hv = *(const f4*)(row + 4 * qs);
        float mm = chunkmax(hv, s & 3, min(4, e - 4 * qs), -FLT_MAX);

        // interior full 4-blocks via level-1
        for (int q = qs + 1; q < qe; ++q)
            mm = fmaxf(mm, lv[q]);

        // tail partial block
        if ((e & 3) && qe > qs) {          // e&3!=0 -> e<=511 -> qe<=127: in-bounds
            f4 tv = *(const f4*)(row + 4 * qe);
            mm = chunkmax(tv, 0, e & 3, mm);
        }

        // half-wave lanes (cl,j) -> 32 consecutive floats: coalesced 128B store
        if (valid)
            out[(size_t)n * (Cc * Sc) + (c0 + cl) * Sc + j] = mm;
    }
}

extern "C" void kernel_launch(void* const* d_in, const int* in_sizes, int n_in,
                              void* d_out, int out_size, void* d_ws, size_t ws_size,
                              hipStream_t stream) {
    const float* sentences = (const float*)d_in[0];
    const int*   rois      = (const int*)d_in[1];
    const int*   roi_idx   = (const int*)d_in[2];
    float*       out       = (float*)d_out;

    roi_pool_occ8<<<Bc * (Cc / CT), 256, 0, stream>>>(sentences, rois, roi_idx, out);
}

// Round 15
// 19.438 us; speedup vs baseline: 1.4084x; 1.0375x over previous
//
#include <hip/hip_runtime.h>
#include <cfloat>

// Problem constants: B=32, C=256, L=512, N=1024, S=8
constexpr int Bc = 32;
constexpr int Cc = 256;
constexpr int Lc = 512;
constexpr int Nc = 1024;
constexpr int Sc = 8;

constexpr int CT      = 8;    // channels per block
constexpr int STRIDE  = 516;  // rowbuf stride (floats): 516%32==4 spreads channel banks
constexpr int LSTRIDE = 132;  // lvl1 stride (floats): 132%32==4 spreads channel banks

typedef float f4 __attribute__((ext_vector_type(4)));

// masked max over chunk elements [lo, hi) (cndmask, no branch)
__device__ __forceinline__ float chunkmax(f4 v, int lo, int hi, float m) {
    float a0 = (lo <= 0 && 0 < hi) ? v.x : -FLT_MAX;
    float a1 = (lo <= 1 && 1 < hi) ? v.y : -FLT_MAX;
    float a2 = (lo <= 2 && 2 < hi) ? v.z : -FLT_MAX;
    float a3 = (lo <= 3 && 3 < hi) ? v.w : -FLT_MAX;
    return fmaxf(fmaxf(m, fmaxf(a0, a1)), fmaxf(a2, a3));
}

// Block = (batch b, 8-channel tile); 1024 blocks, ~25 KB LDS -> 4 resident/CU,
// 16 waves/CU. Proven-deterministic skeleton; lvl1 pyramid with padded stride;
// walk = one wave per bucket item (lane = (cl, j)). Best measured: 19.48 us.
__global__ __launch_bounds__(256) void roi_pool_pyr3(
    const float* __restrict__ sentences,   // (B, C, L)
    const int*   __restrict__ rois,        // (N, 2)
    const int*   __restrict__ roi_idx,     // (N,)
    float*       __restrict__ out)         // (N, C, S)
{
    __shared__ float rowbuf[CT * STRIDE];   // 16,512 B
    __shared__ float lvl1[CT * LSTRIDE];    // 4,224 B: lvl1[r*132+q] = max(row[4q..4q+4))
    __shared__ int   list[Nc];              // 4 KB (worst-case safe)
    __shared__ int   wcnt[16];

    const int bid  = blockIdx.x;           // 0..1023
    const int b    = bid >> 5;             // batch
    const int c0   = (bid & 31) * CT;      // channel tile base
    const int tid  = threadIdx.x;
    const int lane = tid & 63;
    const int w    = tid >> 6;             // wave 0..3

    // ---- ballot compaction scan (proven R8/R10) ----
    int myidx[4], mypos[4];
    #pragma unroll
    for (int q = 0; q < 4; ++q) {
        const int i = q * 256 + tid;
        const int v = roi_idx[i];
        const unsigned long long mask = __ballot(v == b);
        mypos[q] = __popcll(mask & ((1ull << lane) - 1ull));
        myidx[q] = (v == b) ? i : -1;
        if (lane == 0) wcnt[q * 4 + w] = __popcll(mask);
    }

    // ---- staging: load -> ds_write in-loop + level-1 pyramid ----
    {
        const f4* src = (const f4*)(sentences + ((size_t)b * Cc + c0) * Lc);
        #pragma unroll
        for (int i = 0; i < (CT * Lc / 4) / 256; ++i) {   // 4 chunks/thread
            const int idx = tid + i * 256;                // 0..1023
            const int r   = idx >> 7;                     // row 0..7
            const int q   = idx & 127;                    // f4 slot
            f4 v = src[r * (Lc / 4) + q];                 // coalesced 1KB/wave
            *(f4*)(rowbuf + r * STRIDE + 4 * q) = v;      // aligned ds_write_b128
            lvl1[r * LSTRIDE + q] = fmaxf(fmaxf(v.x, v.y), fmaxf(v.z, v.w));
        }
    }
    __syncthreads();   // wcnt + rowbuf + lvl1 visible

    // ---- deterministic prefix over wcnt (verbatim) ----
    int wb0 = 0, wb1 = 0, wb2 = 0, wb3 = 0, run = 0;
    #pragma unroll
    for (int t = 0; t < 16; ++t) {
        if (t == w)      wb0 = run;
        if (t == 4 + w)  wb1 = run;
        if (t == 8 + w)  wb2 = run;
        if (t == 12 + w) wb3 = run;
        run += wcnt[t];
    }
    const int m = run;                     // bucket size for batch b

    if (myidx[0] >= 0) list[wb0 + mypos[0]] = myidx[0];
    if (myidx[1] >= 0) list[wb1 + mypos[1]] = myidx[1];
    if (myidx[2] >= 0) list[wb2 + mypos[2]] = myidx[2];
    if (myidx[3] >= 0) list[wb3 + mypos[3]] = myidx[3];
    __syncthreads();   // list visible

    // ---- bin maxes: wave w handles items w, w+4, ...; lane = (cl, j) ----
    const int cl = lane >> 3;              // channel within tile 0..7
    const int j  = lane & 7;               // bin
    const float* row = rowbuf + cl * STRIDE;
    const float* lv  = lvl1 + cl * LSTRIDE;

    for (int i = w; i < m; i += 4) {
        const int n  = list[i];            // wave-uniform
        const int x1 = rois[2 * n];
        const int x2 = rois[2 * n + 1];
        const int lr = x2 - x1;            // 1..512
        const int s  = x1 + ((j * lr) >> 3);
        const int e  = x1 + (((j + 1) * lr + Sc - 1) >> 3);   // > s always

        const int qs = s >> 2;
        const int qe = e >> 2;

        // head chunk [s, min(e, 4qs+4)) — masked f4
        f4 hv = *(const f4*)(row + 4 * qs);
        float mm = chunkmax(hv, s & 3, min(4, e - 4 * qs), -FLT_MAX);

        // interior full 4-blocks via level-1 (padded stride: ~2-way banks)
        for (int q = qs + 1; q < qe; ++q)
            mm = fmaxf(mm, lv[q]);

        // tail partial block (exists only if e&3 and distinct from head)
        if ((e & 3) && qe > qs) {          // e&3!=0 -> e<=511 -> qe<=127: in-bounds
            f4 tv = *(const f4*)(row + 4 * qe);
            mm = chunkmax(tv, 0, e & 3, mm);
        }

        // wave lanes (cl,j) -> 64 consecutive floats: coalesced 256B store
        out[(size_t)n * (Cc * Sc) + (c0 + cl) * Sc + j] = mm;
    }
}

extern "C" void kernel_launch(void* const* d_in, const int* in_sizes, int n_in,
                              void* d_out, int out_size, void* d_ws, size_t ws_size,
                              hipStream_t stream) {
    const float* sentences = (const float*)d_in[0];
    const int*   rois      = (const int*)d_in[1];
    const int*   roi_idx   = (const int*)d_in[2];
    float*       out       = (float*)d_out;

    roi_pool_pyr3<<<Bc * (Cc / CT), 256, 0, stream>>>(sentences, rois, roi_idx, out);
}